// Round 1
// baseline (476.396 us; speedup 1.0000x reference)
//
#include <hip/hip_runtime.h>
#include <stdint.h>

// Problem constants (match reference: B=64, D=8, N=2048, L=64)
#define B_ 64
#define D_ 8
#define N_ 2048
#define L_ 64

#define WAVES_PER_BLOCK 4
#define PAIRS_PER_WAVE 16
// grid = B_*N_ / (WAVES_PER_BLOCK*PAIRS_PER_WAVE) = 131072/64 = 2048 blocks

typedef float f32x4 __attribute__((ext_vector_type(4)));

__device__ __forceinline__ bool is_ninf(float v) {
    // exact -inf bit pattern; immune to -ffast-math folding of inf compares
    return __float_as_uint(v) == 0xFF800000u;
}

// One wave (64 lanes) handles PAIRS_PER_WAVE consecutive (b,n) pairs (same b:
// start index is a multiple of 16 and N is a multiple of 16). Lane layout per
// pair: g = lane>>4 selects row group (4 rows per float4-load step), c = lane&15
// selects the float4 within the 64-float row. Rows g and g+4 via two loads.
__global__ __launch_bounds__(256) void imputer_kernel(const float* __restrict__ x,
                                                      float* __restrict__ out) {
    const int lane = threadIdx.x & 63;
    const int wave = threadIdx.x >> 6;
    const int wgid = blockIdx.x * WAVES_PER_BLOCK + wave;   // global wave id
    const int p0i  = wgid * PAIRS_PER_WAVE;                 // first (b,n) pair
    const int b    = p0i >> 11;                             // p0i / N_ (uniform over the 16 pairs)
    const int n0   = p0i & (N_ - 1);

    const size_t rstride = (size_t)N_ * L_;                 // stride between d-rows
    const size_t base    = (size_t)b * (D_ * rstride) + (size_t)n0 * L_;

    const int g = lane >> 4;                                // 0..3 (row within load step)
    const int c = lane & 15;                                // float4 index within row

    // 8 sequential streams; per-iteration offsets are it*L_*4 = it*256 B,
    // all 16 fit the 13-bit signed immediate -> zero per-iter address VALU.
    const float* pa = x   + base + (size_t)g       * rstride + (size_t)c * 4;
    const float* pb = x   + base + (size_t)(g + 4) * rstride + (size_t)c * 4;
    float*       qa = out + base + (size_t)g       * rstride + (size_t)c * 4;
    float*       qb = out + base + (size_t)(g + 4) * rstride + (size_t)c * 4;

#pragma unroll 4
    for (int it = 0; it < PAIRS_PER_WAVE; ++it) {
        f32x4 v0 = *(const f32x4*)(pa + (size_t)it * L_);   // rows 0..3
        f32x4 v1 = *(const f32x4*)(pb + (size_t)it * L_);   // rows 4..7

        const bool m0x = is_ninf(v0[0]), m0y = is_ninf(v0[1]), m0z = is_ninf(v0[2]), m0w = is_ninf(v0[3]);
        const bool m1x = is_ninf(v1[0]), m1y = is_ninf(v1[1]), m1z = is_ninf(v1[2]), m1w = is_ninf(v1[3]);

        // Per-component ballots: the v_cmp masks already exist as lane masks;
        // each ballot's 16-bit field [16*d, 16*d+16) holds element {c*4+comp}
        // miss bits of row d (rows 0..3 in *0, rows 4..7 in *1).
        const unsigned long long bx0 = __ballot(m0x), by0 = __ballot(m0y), bz0 = __ballot(m0z), bw0 = __ballot(m0w);
        const unsigned long long bx1 = __ballot(m1x), by1 = __ballot(m1y), bz1 = __ballot(m1z), bw1 = __ballot(m1w);
        const unsigned long long any0 = bx0 | by0 | bz0 | bw0;
        const unsigned long long any1 = bx1 | by1 | bz1 | bw1;

        // rowmiss bit d set iff row d of this (b,n) has any -inf. Wave-uniform.
        unsigned mask8 = 0;
#pragma unroll
        for (int d = 0; d < 4; ++d) {
            if ((any0 >> (16 * d)) & 0xFFFFull) mask8 |= 1u << d;
            if ((any1 >> (16 * d)) & 0xFFFFull) mask8 |= 1u << (d + 4);
        }

        float mean = 0.0f;
        if (mask8) {  // wave-uniform branch (mask8 derived from ballots)
            const int d0 = __ffs(mask8) - 1;      // smallest d with a missing entry
            const int h0 = d0 >> 2;               // which load step holds row d0
            const int g0 = d0 & 3;                // which lane group holds row d0
            const int sh = 16 * g0;               // ballot field shift AND lane index of group base

            // observed count of row d0: pure SALU popcounts, no cross-lane ops
            const unsigned fx = (unsigned)((h0 ? bx1 : bx0) >> sh) & 0xFFFFu;
            const unsigned fy = (unsigned)((h0 ? by1 : by0) >> sh) & 0xFFFFu;
            const unsigned fz = (unsigned)((h0 ? bz1 : bz0) >> sh) & 0xFFFFu;
            const unsigned fw = (unsigned)((h0 ? bw1 : bw0) >> sh) & 0xFFFFu;
            const int cnt = 64 - (__popc(fx) + __popc(fy) + __popc(fz) + __popc(fw));

            // observed sum of row d0: only the g0 lane-group contributes
            float psl = 0.0f;
            if (g == g0) {
                const f32x4 vv = h0 ? v1 : v0;
                if (!is_ninf(vv[0])) psl += vv[0];
                if (!is_ninf(vv[1])) psl += vv[1];
                if (!is_ninf(vv[2])) psl += vv[2];
                if (!is_ninf(vv[3])) psl += vv[3];
            }
            // 4-step butterfly within the 16-lane group (xor<16 stays in group)
            psl += __shfl_xor(psl, 1, 64);
            psl += __shfl_xor(psl, 2, 64);
            psl += __shfl_xor(psl, 4, 64);
            psl += __shfl_xor(psl, 8, 64);
            // broadcast group g0's total to all 64 lanes via scalar readlane
            const float ps = __uint_as_float(
                __builtin_amdgcn_readlane(__float_as_uint(psl), sh));
            mean = (cnt > 0) ? ps / (float)cnt : 0.0f;   // all-missing row -> 0
        }

        v0[0] = m0x ? mean : v0[0];
        v0[1] = m0y ? mean : v0[1];
        v0[2] = m0z ? mean : v0[2];
        v0[3] = m0w ? mean : v0[3];
        v1[0] = m1x ? mean : v1[0];
        v1[1] = m1y ? mean : v1[1];
        v1[2] = m1z ? mean : v1[2];
        v1[3] = m1w ? mean : v1[3];

        // output is never re-read: non-temporal stores keep the 268 MB write
        // stream from churning L2/LLC
        __builtin_nontemporal_store(v0, (f32x4*)(qa + (size_t)it * L_));
        __builtin_nontemporal_store(v1, (f32x4*)(qb + (size_t)it * L_));
    }
}

extern "C" void kernel_launch(void* const* d_in, const int* in_sizes, int n_in,
                              void* d_out, int out_size, void* d_ws, size_t ws_size,
                              hipStream_t stream) {
    const float* x = (const float*)d_in[0];
    float* out = (float*)d_out;
    const int blocks = (B_ * N_) / (WAVES_PER_BLOCK * PAIRS_PER_WAVE);  // 2048
    imputer_kernel<<<blocks, 256, 0, stream>>>(x, out);
}

// Round 2
// 419.348 us; speedup vs baseline: 1.1360x; 1.1360x over previous
//
#include <hip/hip_runtime.h>
#include <stdint.h>

// Problem constants (match reference: B=64, D=8, N=2048, L=64)
#define B_ 64
#define D_ 8
#define N_ 2048
#define L_ 64

typedef float f32x4 __attribute__((ext_vector_type(4)));

__device__ __forceinline__ bool is_ninf(float v) {
    // exact -inf bit pattern; immune to -ffast-math folding of inf compares
    return __float_as_uint(v) == 0xFF800000u;
}

// One wave (64 lanes) handles one (b,n): all D=8 rows of L=64 floats.
// Lane layout: g = lane>>4 selects row group (4 rows per float4-load step),
// c = lane&15 selects the float4 within the 64-float row. Rows g and g+4.
// 32768 blocks x 4 waves = 131072 waves (1 per pair): ~512 waves queued per
// CU so load/shuffle latency is hidden by TLP (round-1 showed 32/CU is not
// enough: 189us latency-bound at 27% HBM).
__global__ __launch_bounds__(256) void imputer_kernel(const float* __restrict__ x,
                                                      float* __restrict__ out) {
    const int lane = threadIdx.x & 63;
    const int wave = threadIdx.x >> 6;
    const int p    = blockIdx.x * 4 + wave;      // (b,n) pair index, 0..B*N-1
    const int b    = p >> 11;                    // p / N_
    const int n    = p & (N_ - 1);               // p % N_

    const size_t rstride = (size_t)N_ * L_;      // stride between d-rows
    const size_t base    = (size_t)b * (D_ * rstride) + (size_t)n * L_;

    const int g = lane >> 4;                     // 0..3 (row within load step)
    const int c = lane & 15;                     // float4 index within row

    const float* p0 = x + base + (size_t)g       * rstride + (size_t)c * 4;
    const float* p1 = x + base + (size_t)(g + 4) * rstride + (size_t)c * 4;

    f32x4 v0 = *(const f32x4*)p0;                // rows 0..3
    f32x4 v1 = *(const f32x4*)p1;                // rows 4..7

    const bool m0x = is_ninf(v0[0]), m0y = is_ninf(v0[1]), m0z = is_ninf(v0[2]), m0w = is_ninf(v0[3]);
    const bool m1x = is_ninf(v1[0]), m1y = is_ninf(v1[1]), m1z = is_ninf(v1[2]), m1w = is_ninf(v1[3]);

    // Per-component ballots: each 16-bit field [16*d, 16*d+16) holds the miss
    // bits of component {comp} across the 16 float4s of row d (rows 0..3 in
    // *0, rows 4..7 in *1). The v_cmp results already exist; ORs are scalar.
    const unsigned long long bx0 = __ballot(m0x), by0 = __ballot(m0y), bz0 = __ballot(m0z), bw0 = __ballot(m0w);
    const unsigned long long bx1 = __ballot(m1x), by1 = __ballot(m1y), bz1 = __ballot(m1z), bw1 = __ballot(m1w);
    const unsigned long long any0 = bx0 | by0 | bz0 | bw0;
    const unsigned long long any1 = bx1 | by1 | bz1 | bw1;

    // rowmiss bit d set iff row d of this (b,n) has any -inf. Wave-uniform.
    unsigned mask8 = 0;
#pragma unroll
    for (int d = 0; d < 4; ++d) {
        if ((any0 >> (16 * d)) & 0xFFFFull) mask8 |= 1u << d;
        if ((any1 >> (16 * d)) & 0xFFFFull) mask8 |= 1u << (d + 4);
    }

    float mean = 0.0f;
    if (mask8) {  // wave-uniform branch (mask8 derived from ballots)
        const int d0 = __ffs(mask8) - 1;         // smallest d with a missing entry
        const int h0 = d0 >> 2;                  // which load step holds row d0
        const int g0 = d0 & 3;                   // which lane group holds row d0
        const int sh = 16 * g0;                  // ballot field shift AND base lane of group g0

        // observed count of row d0: pure SALU popcounts, no cross-lane ops
        const unsigned fx = (unsigned)((h0 ? bx1 : bx0) >> sh) & 0xFFFFu;
        const unsigned fy = (unsigned)((h0 ? by1 : by0) >> sh) & 0xFFFFu;
        const unsigned fz = (unsigned)((h0 ? bz1 : bz0) >> sh) & 0xFFFFu;
        const unsigned fw = (unsigned)((h0 ? bw1 : bw0) >> sh) & 0xFFFFu;
        const int cnt = 64 - (__popc(fx) + __popc(fy) + __popc(fz) + __popc(fw));

        // observed sum of row d0: only the g0 lane-group contributes
        float psl = 0.0f;
        if (g == g0) {
            const f32x4 vv = h0 ? v1 : v0;
            if (!is_ninf(vv[0])) psl += vv[0];
            if (!is_ninf(vv[1])) psl += vv[1];
            if (!is_ninf(vv[2])) psl += vv[2];
            if (!is_ninf(vv[3])) psl += vv[3];
        }
        // 4-step butterfly within the 16-lane group (xor<16 stays in group);
        // replaces the old 6-step x 2-value 64-lane butterfly (12 dependent
        // cross-lane ops) with 4.
        psl += __shfl_xor(psl, 1, 64);
        psl += __shfl_xor(psl, 2, 64);
        psl += __shfl_xor(psl, 4, 64);
        psl += __shfl_xor(psl, 8, 64);
        // broadcast group g0's total to all 64 lanes via scalar readlane
        const float ps = __uint_as_float(
            __builtin_amdgcn_readlane(__float_as_uint(psl), sh));
        mean = (cnt > 0) ? ps / (float)cnt : 0.0f;  // all-missing row -> 0
    }

    v0[0] = m0x ? mean : v0[0];
    v0[1] = m0y ? mean : v0[1];
    v0[2] = m0z ? mean : v0[2];
    v0[3] = m0w ? mean : v0[3];
    v1[0] = m1x ? mean : v1[0];
    v1[1] = m1y ? mean : v1[1];
    v1[2] = m1z ? mean : v1[2];
    v1[3] = m1w ? mean : v1[3];

    float* q0 = out + base + (size_t)g       * rstride + (size_t)c * 4;
    float* q1 = out + base + (size_t)(g + 4) * rstride + (size_t)c * 4;
    *(f32x4*)q0 = v0;
    *(f32x4*)q1 = v1;
}

extern "C" void kernel_launch(void* const* d_in, const int* in_sizes, int n_in,
                              void* d_out, int out_size, void* d_ws, size_t ws_size,
                              hipStream_t stream) {
    const float* x = (const float*)d_in[0];
    float* out = (float*)d_out;
    const int pairs = B_ * N_;                   // 131072 (b,n) pairs
    const int blocks = pairs / 4;                // 4 waves per 256-thread block
    imputer_kernel<<<blocks, 256, 0, stream>>>(x, out);
}